// Round 8
// baseline (193.789 us; speedup 1.0000x reference)
//
#include <hip/hip_runtime.h>
#include <math.h>

#define D 64
#define K 512
#define N_TOK (32 * 4096)            // 131072 tokens
#define TPB 256                      // tokens per screen block (8 waves x 32)
#define EPS 1e-4f                    // screen ambiguity margin (worst-case err ~1.5e-5)
#define FLAG_CAP 8192

// output layout (all f32, concatenated in reference return order)
#define Q_OFF    0
#define LOSS_OFF 8388608
#define PERP_OFF 8388609
#define ENC_OFF  8388610
#define MIND_OFF 8519682

// ws layout (floats): [0..511] b2 ; [512] S ; [514..1025] counts(int) ;
//                     [1026] nflag(int) ; [1028..1028+FLAG_CAP) flag list(int)

typedef __attribute__((ext_vector_type(8))) short  short8;   // 8 bf16 (4 VGPR)
typedef __attribute__((ext_vector_type(4))) short  short4v;
typedef __attribute__((ext_vector_type(4))) float  f32x4;

__device__ __forceinline__ short f2bf(float x) {             // RNE f32->bf16 bits
    unsigned u = __builtin_bit_cast(unsigned, x);
    unsigned r = (u + 0x7fffu + ((u >> 16) & 1u)) >> 16;
    return (short)r;
}
__device__ __forceinline__ float bf2f(short s) {
    unsigned u = ((unsigned)(unsigned short)s) << 16;
    return __builtin_bit_cast(float, u);
}
__device__ __forceinline__ f32x4 mfma16(short8 a, short8 b, f32x4 c) {
    return __builtin_amdgcn_mfma_f32_16x16x32_bf16(a, b, c, 0, 0, 0);
}

// numpy pairwise_sum, n=64, scalar 8-accumulator order on fl(x*x)
__device__ __forceinline__ float np_sumsq64(const float* x) {
    float r[8];
    #pragma unroll
    for (int j = 0; j < 8; ++j) r[j] = __fmul_rn(x[j], x[j]);
    #pragma unroll
    for (int i = 8; i < 64; i += 8) {
        #pragma unroll
        for (int j = 0; j < 8; ++j)
            r[j] = __fadd_rn(r[j], __fmul_rn(x[i + j], x[i + j]));
    }
    float l = __fadd_rn(__fadd_rn(r[0], r[1]), __fadd_rn(r[2], r[3]));
    float h = __fadd_rn(__fadd_rn(r[4], r[5]), __fadd_rn(r[6], r[7]));
    return __fadd_rn(l, h);
}

__global__ void vq_prep(const float* __restrict__ ew, float* __restrict__ b2) {
    int k = threadIdx.x;
    if (k < K) {
        float row[D];
        const float* p = ew + (size_t)k * D;
        #pragma unroll
        for (int d = 0; d < D; ++d) row[d] = p[d];
        b2[k] = np_sumsq64(row);
    }
}

// MFMA screen: scores m~ = z.e - 0.5||e||^2 via 3-term bf16 decomposition.
// A = 16-code tiles (LDS, swizzled, dbuf); B = 32 tokens/wave in registers.
__global__ __launch_bounds__(512, 4) void vq_screen(
    const float* __restrict__ z, const float* __restrict__ ew,
    const float* __restrict__ b2, float* __restrict__ out,
    float* __restrict__ S, int* __restrict__ gcnt,
    int* __restrict__ nflag, int* __restrict__ flist)
{
    __shared__ __align__(16) short s_e[2][2][32 * 64];   // [buf][hi/lo][32 codes x 64]
    __shared__ __align__(16) float s_hb2[K];
    __shared__ int s_cnt[K];

    const int tid  = threadIdx.x;
    const int wid  = tid >> 6, lane = tid & 63;
    const int col  = lane & 15, g = (lane >> 4) & 3;     // token-col / k-group
    const int tbase = blockIdx.x * TPB + wid * 32;

    s_cnt[tid] = 0;
    s_hb2[tid] = 0.5f * b2[tid];

    // ---- B-frags: this wave's 32 tokens, hi/lo bf16, plus sum z^2 slices ----
    short8 zhi[2][2], zlo[2][2];
    float zss = 0.f;
    #pragma unroll
    for (int t = 0; t < 2; ++t) {
        const f32x4* zr = (const f32x4*)(z + (size_t)(tbase + t * 16 + col) * D);
        #pragma unroll
        for (int f = 0; f < 2; ++f) {
            f32x4 va = zr[f * 8 + g * 2], vb = zr[f * 8 + g * 2 + 1];
            float v[8] = {va[0], va[1], va[2], va[3], vb[0], vb[1], vb[2], vb[3]};
            short8 h8, l8;
            #pragma unroll
            for (int j = 0; j < 8; ++j) {
                float x = v[j];
                short hs = f2bf(x);
                h8[j] = hs;
                l8[j] = f2bf(__fsub_rn(x, bf2f(hs)));
                zss = fmaf(x, x, zss);
            }
            zhi[t][f] = h8; zlo[t][f] = l8;
        }
    }

    // ---- codebook chunk staging: 32 codes -> hi/lo bf16, XOR-swizzled ----
#define STAGE(cc, nb) do {                                                   \
        int r_ = tid >> 4, dc_ = tid & 15;                                   \
        f32x4 v_ = *(const f32x4*)(ew + (size_t)((cc) * 32 + r_) * D + dc_ * 4); \
        short h_[4], l_[4];                                                  \
        _Pragma("unroll")                                                    \
        for (int j_ = 0; j_ < 4; ++j_) {                                     \
            h_[j_] = f2bf(v_[j_]);                                           \
            l_[j_] = f2bf(__fsub_rn(v_[j_], bf2f(h_[j_])));                  \
        }                                                                    \
        int off_ = r_ * 64 + (((dc_ >> 1) ^ (r_ & 7)) << 3) + (dc_ & 1) * 4; \
        *(short4v*)&s_e[nb][0][off_] = (short4v){h_[0], h_[1], h_[2], h_[3]};\
        *(short4v*)&s_e[nb][1][off_] = (short4v){l_[0], l_[1], l_[2], l_[3]};\
    } while (0)

    STAGE(0, 0);
    __syncthreads();

    float b1[2] = {-1e30f, -1e30f}, b2s[2] = {-1e30f, -1e30f};
    int   k1[2] = {0, 0};

    for (int c = 0; c < 16; ++c) {
        const int b = c & 1;
        if (c < 15) STAGE(c + 1, b ^ 1);
        #pragma unroll
        for (int sub = 0; sub < 2; ++sub) {
            const int rr = sub * 16 + col;                 // A-row (code) this lane loads
            short8 ahi[2], alo[2];
            #pragma unroll
            for (int f = 0; f < 2; ++f) {
                int off = rr * 64 + ((((f << 2) + g) ^ (rr & 7)) << 3);
                ahi[f] = *(const short8*)&s_e[b][0][off];
                alo[f] = *(const short8*)&s_e[b][1][off];
            }
            const int c0 = c * 32 + sub * 16 + g * 4;      // codes this lane scores
            f32x4 hb = *(const f32x4*)&s_hb2[c0];
            #pragma unroll
            for (int t = 0; t < 2; ++t) {
                f32x4 acc = (f32x4){0.f, 0.f, 0.f, 0.f};
                acc = mfma16(ahi[0], zhi[t][0], acc);
                acc = mfma16(ahi[1], zhi[t][1], acc);
                acc = mfma16(ahi[0], zlo[t][0], acc);
                acc = mfma16(ahi[1], zlo[t][1], acc);
                acc = mfma16(alo[0], zhi[t][0], acc);
                acc = mfma16(alo[1], zhi[t][1], acc);
                #pragma unroll
                for (int r = 0; r < 4; ++r) {
                    float sc = acc[r] - hb[r];
                    if (sc > b1[t]) { b2s[t] = b1[t]; b1[t] = sc; k1[t] = c0 + r; }
                    else            { b2s[t] = fmaxf(b2s[t], sc); }
                }
            }
        }
        __syncthreads();
    }

    // ---- cross-lane merge over the 4 k-groups (lanes stride 16) ----
    #pragma unroll
    for (int t = 0; t < 2; ++t) {
        #pragma unroll
        for (int m = 16; m < 64; m <<= 1) {
            float ob = __shfl_xor(b1[t], m);
            float os = __shfl_xor(b2s[t], m);
            int   ok = __shfl_xor(k1[t], m);
            if (ob > b1[t])       { b2s[t] = fmaxf(b1[t], os); b1[t] = ob; k1[t] = ok; }
            else if (ob == b1[t]) { b2s[t] = b1[t]; if (ok < k1[t]) k1[t] = ok; }  // tie -> flag
            else                  { b2s[t] = fmaxf(b2s[t], ob); }
        }
    }

    if (lane < 16) {
        #pragma unroll
        for (int t = 0; t < 2; ++t) {
            int tok = tbase + t * 16 + col;
            out[ENC_OFF + tok] = (float)k1[t];
            atomicAdd(&s_cnt[k1[t]], 1);
            if (b1[t] - b2s[t] < EPS) {                    // ambiguous: exact re-check
                int slot = atomicAdd(nflag, 1);
                if (slot < FLAG_CAP) flist[slot] = tok;
            }
        }
    }

    // S = sum ||z||^2 - 2 * sum best_score  (loss/mind thresholds are huge)
    float contrib = zss + ((lane < 16) ? -2.f * (b1[0] + b1[1]) : 0.f);
    #pragma unroll
    for (int off = 32; off; off >>= 1) contrib += __shfl_down(contrib, off);
    if (lane == 0) atomicAdd(S, contrib);

    __syncthreads();
    int cc = s_cnt[tid];
    if (cc) atomicAdd(&gcnt[tid], cc);
#undef STAGE
}

// exact numpy-f32 rescan of flagged tokens: one token per wave, code per lane
__global__ __launch_bounds__(64) void vq_refine(
    const float* __restrict__ z, const float* __restrict__ ew,
    const float* __restrict__ b2, float* __restrict__ out,
    int* __restrict__ gcnt, const int* __restrict__ nflag,
    const int* __restrict__ flist)
{
    const int lane = threadIdx.x;
    int nf = *nflag; if (nf > FLAG_CAP) nf = FLAG_CAP;

    for (int i = blockIdx.x; i < nf; i += gridDim.x) {
        const int tok = flist[i];
        float zf[D];
        const float* zr = z + (size_t)tok * D;
        #pragma unroll
        for (int d = 0; d < D; ++d) zf[d] = zr[d];
        const float an = np_sumsq64(zf);

        float bd = 1e30f; int bk = 0;
        #pragma unroll 1
        for (int j = 0; j < 8; ++j) {
            const int c = j * 64 + lane;
            const float* e0 = ew + (size_t)c * D;
            float gacc = 0.f;
            #pragma unroll
            for (int d = 0; d < D; ++d) gacc = fmaf(zf[d], e0[d], gacc);
            float dd = fmaf(-2.f, gacc, __fadd_rn(an, b2[c]));
            if (dd < bd) { bd = dd; bk = c; }              // lane-ascending codes
        }
        #pragma unroll
        for (int off = 32; off; off >>= 1) {               // min-d, min-index
            float obd = __shfl_down(bd, off);
            int   obk = __shfl_down(bk, off);
            if (obd < bd || (obd == bd && obk < bk)) { bd = obd; bk = obk; }
        }
        bk = __shfl(bk, 0);
        if (lane == 0) {
            int old = (int)out[ENC_OFF + tok];
            if (old != bk) {
                out[ENC_OFF + tok] = (float)bk;
                atomicAdd(&gcnt[bk], 1);
                atomicAdd(&gcnt[old], -1);
            }
        }
    }
}

// quantized_st = fl(z + fl(e - z)) elementwise, from final enc
__global__ __launch_bounds__(256) void vq_gather(
    const float* __restrict__ z, const float* __restrict__ ew,
    float* __restrict__ out)
{
    const int i   = blockIdx.x * 256 + threadIdx.x;        // 0 .. N_TOK*16-1
    const int tok = i >> 4, dc = i & 15;
    const int bk  = (int)out[ENC_OFF + tok];
    f32x4 e  = *(const f32x4*)(ew + (size_t)bk * D + dc * 4);
    f32x4 zv = *(const f32x4*)(z + (size_t)tok * D + dc * 4);
    f32x4 o;
    #pragma unroll
    for (int r = 0; r < 4; ++r) o[r] = __fadd_rn(zv[r], __fsub_rn(e[r], zv[r]));
    *(f32x4*)(out + Q_OFF + (size_t)tok * D + dc * 4) = o;
}

__global__ void vq_fin(const float* __restrict__ S, const int* __restrict__ gcnt,
                       float* __restrict__ out)
{
    __shared__ float red[8];
    int t = threadIdx.x;               // 512 threads, one per code
    float p = (float)gcnt[t] * (1.f / (float)N_TOK);
    float term = p * logf(p + 1e-10f);
    #pragma unroll
    for (int off = 32; off; off >>= 1) term += __shfl_down(term, off);
    if ((t & 63) == 0) red[t >> 6] = term;
    __syncthreads();
    if (t == 0) {
        float s = 0.f;
        #pragma unroll
        for (int i = 0; i < 8; ++i) s += red[i];
        float Sv = S[0];
        out[PERP_OFF] = expf(-s);
        out[LOSS_OFF] = 1.25f * Sv * (1.f / (float)(N_TOK * D));
        out[MIND_OFF] = Sv * (1.f / (float)N_TOK);
    }
}

extern "C" void kernel_launch(void* const* d_in, const int* in_sizes, int n_in,
                              void* d_out, int out_size, void* d_ws, size_t ws_size,
                              hipStream_t stream)
{
    const float* z  = (const float*)d_in[0];
    const float* ew = (const float*)d_in[1];
    float* out = (float*)d_out;
    float* wsf = (float*)d_ws;

    float* Sp    = wsf + 512;
    int*   gcnt  = (int*)(wsf + 514);
    int*   nflag = (int*)(wsf + 1026);
    int*   flist = (int*)(wsf + 1028);

    // zero S, counts, flag counter each call (graph replays don't re-poison)
    hipMemsetAsync(wsf + 512, 0, 516 * sizeof(float), stream);

    vq_prep<<<1, 512, 0, stream>>>(ew, wsf);
    vq_screen<<<N_TOK / TPB, 512, 0, stream>>>(z, ew, wsf, out, Sp, gcnt, nflag, flist);
    vq_refine<<<1024, 64, 0, stream>>>(z, ew, wsf, out, gcnt, nflag, flist);
    vq_gather<<<(N_TOK * 16) / 256, 256, 0, stream>>>(z, ew, out);
    vq_fin<<<1, 512, 0, stream>>>(Sp, gcnt, out);
}